// Round 1
// baseline (602.428 us; speedup 1.0000x reference)
//
#include <hip/hip_runtime.h>
#include <hip/hip_bf16.h>

#define IN_DIM 1024
#define HID 128
#define LAT 64

// ---------- CSR construction ----------

__global__ __launch_bounds__(256) void k_init(int* deg, int* cursor, int n) {
    int i = blockIdx.x * 256 + threadIdx.x;
    if (i < n) { deg[i] = 1; cursor[i] = 0; }   // deg starts at 1: self-loop
}

__global__ __launch_bounds__(256) void k_count(const int* __restrict__ ei, int* deg, int E) {
    int e = blockIdx.x * 256 + threadIdx.x;
    if (e < E) atomicAdd(&deg[ei[E + e]], 1);   // recv = ei[E + e]
}

__global__ __launch_bounds__(256) void k_dis(const int* __restrict__ deg, float* dis, int n) {
    int i = blockIdx.x * 256 + threadIdx.x;
    if (i < n) dis[i] = rsqrtf((float)deg[i]);
}

__global__ __launch_bounds__(1024) void k_scan(const int* __restrict__ deg, int* __restrict__ rowptr, int n) {
    __shared__ int sh[1024];
    __shared__ int carry_sh;
    int t = threadIdx.x;
    if (t == 0) { carry_sh = 0; rowptr[0] = 0; }
    __syncthreads();
    int nch = (n + 1023) >> 10;
    for (int ch = 0; ch < nch; ++ch) {
        int i = (ch << 10) + t;
        sh[t] = (i < n) ? deg[i] : 0;
        __syncthreads();
        for (int off = 1; off < 1024; off <<= 1) {
            int add = (t >= off) ? sh[t - off] : 0;
            __syncthreads();
            sh[t] += add;
            __syncthreads();
        }
        int carry = carry_sh;
        int inc = sh[t] + carry;
        if (i < n) rowptr[i + 1] = inc;
        int total = sh[1023];
        __syncthreads();
        if (t == 0) carry_sh = carry + total;
        __syncthreads();
    }
}

__global__ __launch_bounds__(256) void k_fill(const int* __restrict__ ei, const int* __restrict__ rowptr,
                                              int* cursor, const float* __restrict__ dis,
                                              int* __restrict__ colA, float* __restrict__ valA,
                                              int n, int E) {
    int e = blockIdx.x * 256 + threadIdx.x;
    if (e >= E + n) return;
    int s, r;
    if (e < E) { s = ei[e]; r = ei[E + e]; }
    else       { s = r = e - E; }            // self-loop
    int p = atomicAdd(&cursor[r], 1);
    int idx = rowptr[r] + p;
    colA[idx] = s;
    valA[idx] = dis[s] * dis[r];
}

// ---------- SpMM: out[i,:] = (bias) + sum_{p in row i} val[p] * H[col[p],:], optional relu ----------

template<int F, bool BIAS, bool RELU>
__global__ __launch_bounds__(256) void k_spmm(const float* __restrict__ H,
                                              const int* __restrict__ rowptr,
                                              const int* __restrict__ colA,
                                              const float* __restrict__ valA,
                                              const float* __restrict__ bias,
                                              float* __restrict__ out, int n) {
    int wave = (blockIdx.x * 256 + threadIdx.x) >> 6;
    int lane = threadIdx.x & 63;
    if (wave >= n) return;
    int p0 = rowptr[wave], p1 = rowptr[wave + 1];
    float acc[F / 64];
#pragma unroll
    for (int j = 0; j < F / 64; ++j) acc[j] = 0.f;
    for (int p = p0; p < p1; ++p) {
        int c = colA[p];
        float v = valA[p];
        const float* row = H + (size_t)c * F;
#pragma unroll
        for (int j = 0; j < F / 64; ++j) acc[j] = fmaf(v, row[lane + 64 * j], acc[j]);
    }
#pragma unroll
    for (int j = 0; j < F / 64; ++j) {
        float r = acc[j] + (BIAS ? bias[lane + 64 * j] : 0.f);
        if (RELU) r = fmaxf(r, 0.f);
        out[(size_t)wave * F + lane + 64 * j] = r;
    }
}

// ---------- Dense GEMM: C[M,Nc] = A[M,K] @ B[K,Nc] (+bias, relu). Nc % 64 == 0, K % 16 == 0 ----------

template<bool BIAS, bool RELU>
__global__ __launch_bounds__(256) void k_gemm(const float* __restrict__ A, const float* __restrict__ B,
                                              const float* __restrict__ bias, float* __restrict__ C,
                                              int M, int K, int Nc) {
    __shared__ float As[16][64];   // As[k][m] (transposed)
    __shared__ float Bs[16][64];   // Bs[k][n]
    int tid = threadIdx.x;
    int tx = tid & 15, ty = tid >> 4;
    int m0 = blockIdx.x * 64, n0 = blockIdx.y * 64;
    float acc[4][4] = {};

    for (int k0 = 0; k0 < K; k0 += 16) {
        {
            int idx = tid * 4;
            int r = idx >> 4;          // 0..63 (m within tile)
            int c = idx & 15;          // 0,4,8,12 (k within tile)
            int gr = m0 + r;
            float4 av = (gr < M) ? *(const float4*)&A[(size_t)gr * K + k0 + c]
                                 : make_float4(0.f, 0.f, 0.f, 0.f);
            As[c + 0][r] = av.x; As[c + 1][r] = av.y; As[c + 2][r] = av.z; As[c + 3][r] = av.w;
            int kk = idx >> 6;         // 0..15
            int cc = idx & 63;         // 0,4,..,60
            float4 bv = *(const float4*)&B[(size_t)(k0 + kk) * Nc + n0 + cc];
            *(float4*)&Bs[kk][cc] = bv;
        }
        __syncthreads();
#pragma unroll
        for (int kk = 0; kk < 16; ++kk) {
            float4 av = *(const float4*)&As[kk][ty * 4];
            float4 bv = *(const float4*)&Bs[kk][tx * 4];
            float aa[4] = {av.x, av.y, av.z, av.w};
            float bb[4] = {bv.x, bv.y, bv.z, bv.w};
#pragma unroll
            for (int i = 0; i < 4; ++i)
#pragma unroll
                for (int j = 0; j < 4; ++j)
                    acc[i][j] = fmaf(aa[i], bb[j], acc[i][j]);
        }
        __syncthreads();
    }

    int nbase = n0 + tx * 4;
    float bvals[4] = {0.f, 0.f, 0.f, 0.f};
    if (BIAS) {
#pragma unroll
        for (int j = 0; j < 4; ++j) bvals[j] = bias[nbase + j];
    }
#pragma unroll
    for (int i = 0; i < 4; ++i) {
        int gr = m0 + ty * 4 + i;
        if (gr < M) {
            float v0 = acc[i][0] + bvals[0];
            float v1 = acc[i][1] + bvals[1];
            float v2 = acc[i][2] + bvals[2];
            float v3 = acc[i][3] + bvals[3];
            if (RELU) {
                v0 = fmaxf(v0, 0.f); v1 = fmaxf(v1, 0.f);
                v2 = fmaxf(v2, 0.f); v3 = fmaxf(v3, 0.f);
            }
            *(float4*)&C[(size_t)gr * Nc + nbase] = make_float4(v0, v1, v2, v3);
        }
    }
}

// ---------- struct_recon = S @ S^T, S is [M,64] ----------

__global__ __launch_bounds__(256) void k_sst(const float* __restrict__ S, float* __restrict__ C, int M) {
    __shared__ float SiT[64][64];   // SiT[k][m]
    __shared__ float SjT[64][64];   // SjT[k][n]
    int tid = threadIdx.x;
    int tx = tid & 15, ty = tid >> 4;
    int i0 = blockIdx.x * 64, j0 = blockIdx.y * 64;

#pragma unroll
    for (int it = 0; it < 4; ++it) {
        int linear = it * 1024 + tid * 4;
        int r = linear >> 6;       // 0..63
        int c = linear & 63;       // 0,4,..,60
        int gi = i0 + r;
        float4 v = (gi < M) ? *(const float4*)&S[(size_t)gi * 64 + c] : make_float4(0.f,0.f,0.f,0.f);
        SiT[c + 0][r] = v.x; SiT[c + 1][r] = v.y; SiT[c + 2][r] = v.z; SiT[c + 3][r] = v.w;
        int gj = j0 + r;
        float4 w = (gj < M) ? *(const float4*)&S[(size_t)gj * 64 + c] : make_float4(0.f,0.f,0.f,0.f);
        SjT[c + 0][r] = w.x; SjT[c + 1][r] = w.y; SjT[c + 2][r] = w.z; SjT[c + 3][r] = w.w;
    }
    __syncthreads();

    float acc[4][4] = {};
#pragma unroll 8
    for (int kk = 0; kk < 64; ++kk) {
        float4 av = *(const float4*)&SiT[kk][ty * 4];
        float4 bv = *(const float4*)&SjT[kk][tx * 4];
        float aa[4] = {av.x, av.y, av.z, av.w};
        float bb[4] = {bv.x, bv.y, bv.z, bv.w};
#pragma unroll
        for (int i = 0; i < 4; ++i)
#pragma unroll
            for (int j = 0; j < 4; ++j)
                acc[i][j] = fmaf(aa[i], bb[j], acc[i][j]);
    }

    int gj0 = j0 + tx * 4;
#pragma unroll
    for (int i = 0; i < 4; ++i) {
        int gi = i0 + ty * 4 + i;
        if (gi >= M) continue;
        if (gj0 + 3 < M) {
            *(float4*)&C[(size_t)gi * M + gj0] = make_float4(acc[i][0], acc[i][1], acc[i][2], acc[i][3]);
        } else {
#pragma unroll
            for (int j = 0; j < 4; ++j)
                if (gj0 + j < M) C[(size_t)gi * M + gj0 + j] = acc[i][j];
        }
    }
}

// ---------- launch ----------

extern "C" void kernel_launch(void* const* d_in, const int* in_sizes, int n_in,
                              void* d_out, int out_size, void* d_ws, size_t ws_size,
                              hipStream_t stream) {
    const float* x   = (const float*)d_in[0];
    const int*   ei  = (const int*)d_in[1];
    const float* W1  = (const float*)d_in[2];
    const float* b1  = (const float*)d_in[3];
    const float* W2  = (const float*)d_in[4];
    const float* b2  = (const float*)d_in[5];
    const float* Wa1 = (const float*)d_in[6];
    const float* ba1 = (const float*)d_in[7];
    const float* Wa2 = (const float*)d_in[8];
    const float* ba2 = (const float*)d_in[9];
    const float* Ws  = (const float*)d_in[10];
    const float* bs  = (const float*)d_in[11];

    int N = in_sizes[0] / IN_DIM;
    int E = in_sizes[1] / 2;

    float* out  = (float*)d_out;
    float* attr = out;                              // [N, IN_DIM]
    float* st   = out + (size_t)N * IN_DIM;         // [N, N]
    float* zout = st + (size_t)N * N;               // [N, LAT]

    float* w = (float*)d_ws;
    float* t128a = w; w += (size_t)N * 128;
    float* h     = w; w += (size_t)N * 128;
    float* a     = w; w += (size_t)N * 128;
    float* aa    = w; w += (size_t)N * 128;
    float* t64   = w; w += (size_t)N * 64;
    float* az    = w; w += (size_t)N * 64;
    float* s     = w; w += (size_t)N * 64;
    float* dis   = w; w += N;
    float* valA  = w; w += (E + N);
    int* ip      = (int*)w;
    int* deg     = ip; ip += N;
    int* cursor  = ip; ip += N;
    int* rowptr  = ip; ip += N + 1;
    int* colA    = ip; ip += (E + N);

    dim3 b256(256);
    int mt = (N + 63) / 64;

    // CSR of A_norm (by recv), norm folded into vals
    k_init <<<dim3((N + 255) / 256), b256, 0, stream>>>(deg, cursor, N);
    k_count<<<dim3((E + 255) / 256), b256, 0, stream>>>(ei, deg, E);
    k_dis  <<<dim3((N + 255) / 256), b256, 0, stream>>>(deg, dis, N);
    k_scan <<<dim3(1), dim3(1024), 0, stream>>>(deg, rowptr, N);
    k_fill <<<dim3((E + N + 255) / 256), b256, 0, stream>>>(ei, rowptr, cursor, dis, colA, valA, N, E);

    // encoder: h = relu(A (x W1) + b1); z = relu(A (h W2) + b2)
    k_gemm<false, false><<<dim3(mt, HID / 64), b256, 0, stream>>>(x, W1, nullptr, t128a, N, IN_DIM, HID);
    k_spmm<128, true, true><<<dim3((N * 64 + 255) / 256), b256, 0, stream>>>(t128a, rowptr, colA, valA, b1, h, N);
    k_gemm<false, false><<<dim3(mt, LAT / 64), b256, 0, stream>>>(h, W2, nullptr, t64, N, HID, LAT);
    k_spmm<64, true, true><<<dim3((N * 64 + 255) / 256), b256, 0, stream>>>(t64, rowptr, colA, valA, b2, zout, N);

    // shared propagation: az = A z  (used by both decoders; exact reassociation of reference)
    k_spmm<64, false, false><<<dim3((N * 64 + 255) / 256), b256, 0, stream>>>(zout, rowptr, colA, valA, nullptr, az, N);

    // attribute decoder: a = relu(az Wa1 + ba1); attr = relu((A a) Wa2 + ba2)
    k_gemm<true, true><<<dim3(mt, HID / 64), b256, 0, stream>>>(az, Wa1, ba1, a, N, LAT, HID);
    k_spmm<128, false, false><<<dim3((N * 64 + 255) / 256), b256, 0, stream>>>(a, rowptr, colA, valA, nullptr, aa, N);
    k_gemm<true, true><<<dim3(mt, IN_DIM / 64), b256, 0, stream>>>(aa, Wa2, ba2, attr, N, HID, IN_DIM);

    // structure decoder: s = relu(az Ws + bs); struct = s s^T
    k_gemm<true, true><<<dim3(mt, LAT / 64), b256, 0, stream>>>(az, Ws, bs, s, N, LAT, LAT);
    k_sst<<<dim3(mt, mt), b256, 0, stream>>>(s, st, N);
}

// Round 2
// 476.433 us; speedup vs baseline: 1.2645x; 1.2645x over previous
//
#include <hip/hip_runtime.h>
#include <hip/hip_bf16.h>

#define IN_DIM 1024
#define HID 128
#define LAT 64

typedef __attribute__((ext_vector_type(8))) short bf16x8;
typedef __attribute__((ext_vector_type(4))) float f32x4;

// ---------- CSR construction ----------

__global__ __launch_bounds__(256) void k_init(int* deg, int* cursor, int n) {
    int i = blockIdx.x * 256 + threadIdx.x;
    if (i < n) { deg[i] = 1; cursor[i] = 0; }   // deg starts at 1: self-loop
}

__global__ __launch_bounds__(256) void k_count(const int* __restrict__ ei, int* deg, int E) {
    int e = blockIdx.x * 256 + threadIdx.x;
    if (e < E) atomicAdd(&deg[ei[E + e]], 1);   // recv = ei[E + e]
}

__global__ __launch_bounds__(256) void k_dis(const int* __restrict__ deg, float* dis, int n) {
    int i = blockIdx.x * 256 + threadIdx.x;
    if (i < n) dis[i] = rsqrtf((float)deg[i]);
}

__global__ __launch_bounds__(1024) void k_scan(const int* __restrict__ deg, int* __restrict__ rowptr, int n) {
    __shared__ int sh[1024];
    __shared__ int carry_sh;
    int t = threadIdx.x;
    if (t == 0) { carry_sh = 0; rowptr[0] = 0; }
    __syncthreads();
    int nch = (n + 1023) >> 10;
    for (int ch = 0; ch < nch; ++ch) {
        int i = (ch << 10) + t;
        sh[t] = (i < n) ? deg[i] : 0;
        __syncthreads();
        for (int off = 1; off < 1024; off <<= 1) {
            int add = (t >= off) ? sh[t - off] : 0;
            __syncthreads();
            sh[t] += add;
            __syncthreads();
        }
        int carry = carry_sh;
        int inc = sh[t] + carry;
        if (i < n) rowptr[i + 1] = inc;
        int total = sh[1023];
        __syncthreads();
        if (t == 0) carry_sh = carry + total;
        __syncthreads();
    }
}

__global__ __launch_bounds__(256) void k_fill(const int* __restrict__ ei, const int* __restrict__ rowptr,
                                              int* cursor, const float* __restrict__ dis,
                                              int* __restrict__ colA, float* __restrict__ valA,
                                              int n, int E) {
    int e = blockIdx.x * 256 + threadIdx.x;
    if (e >= E + n) return;
    int s, r;
    if (e < E) { s = ei[e]; r = ei[E + e]; }
    else       { s = r = e - E; }            // self-loop
    int p = atomicAdd(&cursor[r], 1);
    int idx = rowptr[r] + p;
    colA[idx] = s;
    valA[idx] = dis[s] * dis[r];
}

// ---------- SpMM: out[i,:] = (bias) + sum_{p in row i} val[p] * H[col[p],:], optional relu ----------

template<int F, bool BIAS, bool RELU>
__global__ __launch_bounds__(256) void k_spmm(const float* __restrict__ H,
                                              const int* __restrict__ rowptr,
                                              const int* __restrict__ colA,
                                              const float* __restrict__ valA,
                                              const float* __restrict__ bias,
                                              float* __restrict__ out, int n) {
    int wave = (blockIdx.x * 256 + threadIdx.x) >> 6;
    int lane = threadIdx.x & 63;
    if (wave >= n) return;
    int p0 = rowptr[wave], p1 = rowptr[wave + 1];
    float acc[F / 64];
#pragma unroll
    for (int j = 0; j < F / 64; ++j) acc[j] = 0.f;
    for (int p = p0; p < p1; ++p) {
        int c = colA[p];
        float v = valA[p];
        const float* row = H + (size_t)c * F;
#pragma unroll
        for (int j = 0; j < F / 64; ++j) acc[j] = fmaf(v, row[lane + 64 * j], acc[j]);
    }
#pragma unroll
    for (int j = 0; j < F / 64; ++j) {
        float r = acc[j] + (BIAS ? bias[lane + 64 * j] : 0.f);
        if (RELU) r = fmaxf(r, 0.f);
        out[(size_t)wave * F + lane + 64 * j] = r;
    }
}

// ---------- Dense GEMM: C[M,Nc] = A[M,K] @ B[K,Nc] (+bias, relu). Nc % 64 == 0, K % 16 == 0 ----------

template<bool BIAS, bool RELU>
__global__ __launch_bounds__(256) void k_gemm(const float* __restrict__ A, const float* __restrict__ B,
                                              const float* __restrict__ bias, float* __restrict__ C,
                                              int M, int K, int Nc) {
    __shared__ float As[16][64];   // As[k][m] (transposed)
    __shared__ float Bs[16][64];   // Bs[k][n]
    int tid = threadIdx.x;
    int tx = tid & 15, ty = tid >> 4;
    int m0 = blockIdx.x * 64, n0 = blockIdx.y * 64;
    float acc[4][4] = {};

    for (int k0 = 0; k0 < K; k0 += 16) {
        {
            int idx = tid * 4;
            int r = idx >> 4;          // 0..63 (m within tile)
            int c = idx & 15;          // 0,4,8,12 (k within tile)
            int gr = m0 + r;
            float4 av = (gr < M) ? *(const float4*)&A[(size_t)gr * K + k0 + c]
                                 : make_float4(0.f, 0.f, 0.f, 0.f);
            As[c + 0][r] = av.x; As[c + 1][r] = av.y; As[c + 2][r] = av.z; As[c + 3][r] = av.w;
            int kk = idx >> 6;         // 0..15
            int cc = idx & 63;         // 0,4,..,60
            float4 bv = *(const float4*)&B[(size_t)(k0 + kk) * Nc + n0 + cc];
            *(float4*)&Bs[kk][cc] = bv;
        }
        __syncthreads();
#pragma unroll
        for (int kk = 0; kk < 16; ++kk) {
            float4 av = *(const float4*)&As[kk][ty * 4];
            float4 bv = *(const float4*)&Bs[kk][tx * 4];
            float aa[4] = {av.x, av.y, av.z, av.w};
            float bb[4] = {bv.x, bv.y, bv.z, bv.w};
#pragma unroll
            for (int i = 0; i < 4; ++i)
#pragma unroll
                for (int j = 0; j < 4; ++j)
                    acc[i][j] = fmaf(aa[i], bb[j], acc[i][j]);
        }
        __syncthreads();
    }

    int nbase = n0 + tx * 4;
    float bvals[4] = {0.f, 0.f, 0.f, 0.f};
    if (BIAS) {
#pragma unroll
        for (int j = 0; j < 4; ++j) bvals[j] = bias[nbase + j];
    }
#pragma unroll
    for (int i = 0; i < 4; ++i) {
        int gr = m0 + ty * 4 + i;
        if (gr < M) {
            float v0 = acc[i][0] + bvals[0];
            float v1 = acc[i][1] + bvals[1];
            float v2 = acc[i][2] + bvals[2];
            float v3 = acc[i][3] + bvals[3];
            if (RELU) {
                v0 = fmaxf(v0, 0.f); v1 = fmaxf(v1, 0.f);
                v2 = fmaxf(v2, 0.f); v3 = fmaxf(v3, 0.f);
            }
            *(float4*)&C[(size_t)gr * Nc + nbase] = make_float4(v0, v1, v2, v3);
        }
    }
}

// ---------- split fp32 -> (hi, lo) bf16 pair; zero-pads rows [M, Mpad) ----------

__global__ __launch_bounds__(256) void k_split(const float* __restrict__ s,
                                               __hip_bfloat16* __restrict__ hi,
                                               __hip_bfloat16* __restrict__ lo,
                                               int nvalid, int ntotal) {
    int i = blockIdx.x * 256 + threadIdx.x;
    if (i >= ntotal) return;
    float v = (i < nvalid) ? s[i] : 0.f;
    __hip_bfloat16 h = __float2bfloat16(v);
    hi[i] = h;
    lo[i] = __float2bfloat16(v - __bfloat162float(h));
}

// ---------- struct_recon = S @ S^T via split-bf16 MFMA (hi*hi + hi*lo + lo*hi) ----------
// Block = 256 threads = 4 waves (2x2), each wave computes a 64x64 tile -> block tile 128x128.
// Fragment loads are direct global (S tiles are L1/L2 resident): for mfma_f32_16x16x32_bf16,
// A-frag(row=lane&15, k=(lane>>4)*8+e) and B-frag(col=lane&15, same k) are the SAME pattern
// on S (since B = S_j^T), one 16B bf16x8 load each.

__global__ __launch_bounds__(256) void k_sst_mfma(const __hip_bfloat16* __restrict__ Shi,
                                                  const __hip_bfloat16* __restrict__ Slo,
                                                  float* __restrict__ C, int M) {
    int w = threadIdx.x >> 6, lane = threadIdx.x & 63;
    int wr = w >> 1, wc = w & 1;
    int i0 = blockIdx.x * 128 + wr * 64;
    int j0 = blockIdx.y * 128 + wc * 64;
    int lrow = lane & 15;
    int lk = (lane >> 4) * 8;

    f32x4 acc[4][4] = {};   // [mi][nj], each 4 f32 rows

#pragma unroll
    for (int ks = 0; ks < 2; ++ks) {
        bf16x8 ah[4], al[4], bh[4], bl[4];
#pragma unroll
        for (int mi = 0; mi < 4; ++mi) {
            size_t off = (size_t)(i0 + mi * 16 + lrow) * 64 + ks * 32 + lk;
            ah[mi] = *(const bf16x8*)(Shi + off);
            al[mi] = *(const bf16x8*)(Slo + off);
        }
#pragma unroll
        for (int nj = 0; nj < 4; ++nj) {
            size_t off = (size_t)(j0 + nj * 16 + lrow) * 64 + ks * 32 + lk;
            bh[nj] = *(const bf16x8*)(Shi + off);
            bl[nj] = *(const bf16x8*)(Slo + off);
        }
#pragma unroll
        for (int mi = 0; mi < 4; ++mi)
#pragma unroll
            for (int nj = 0; nj < 4; ++nj) {
                acc[mi][nj] = __builtin_amdgcn_mfma_f32_16x16x32_bf16(ah[mi], bh[nj], acc[mi][nj], 0, 0, 0);
                acc[mi][nj] = __builtin_amdgcn_mfma_f32_16x16x32_bf16(ah[mi], bl[nj], acc[mi][nj], 0, 0, 0);
                acc[mi][nj] = __builtin_amdgcn_mfma_f32_16x16x32_bf16(al[mi], bh[nj], acc[mi][nj], 0, 0, 0);
            }
    }

    // C/D layout: col = lane&15, row = (lane>>4)*4 + r  [m89-verified]
    int r0 = (lane >> 4) * 4;
#pragma unroll
    for (int mi = 0; mi < 4; ++mi) {
        int row_b = i0 + mi * 16 + r0;
#pragma unroll
        for (int nj = 0; nj < 4; ++nj) {
            int col = j0 + nj * 16 + lrow;
            if (col < M) {
#pragma unroll
                for (int r = 0; r < 4; ++r) {
                    int row = row_b + r;
                    if (row < M) C[(size_t)row * M + col] = acc[mi][nj][r];
                }
            }
        }
    }
}

// ---------- launch ----------

extern "C" void kernel_launch(void* const* d_in, const int* in_sizes, int n_in,
                              void* d_out, int out_size, void* d_ws, size_t ws_size,
                              hipStream_t stream) {
    const float* x   = (const float*)d_in[0];
    const int*   ei  = (const int*)d_in[1];
    const float* W1  = (const float*)d_in[2];
    const float* b1  = (const float*)d_in[3];
    const float* W2  = (const float*)d_in[4];
    const float* b2  = (const float*)d_in[5];
    const float* Wa1 = (const float*)d_in[6];
    const float* ba1 = (const float*)d_in[7];
    const float* Wa2 = (const float*)d_in[8];
    const float* ba2 = (const float*)d_in[9];
    const float* Ws  = (const float*)d_in[10];
    const float* bs  = (const float*)d_in[11];

    int N = in_sizes[0] / IN_DIM;
    int E = in_sizes[1] / 2;
    int Mpad = ((N + 127) / 128) * 128;

    float* out  = (float*)d_out;
    float* attr = out;                              // [N, IN_DIM]
    float* st   = out + (size_t)N * IN_DIM;         // [N, N]
    float* zout = st + (size_t)N * N;               // [N, LAT]

    float* w = (float*)d_ws;
    float* t128a = w; w += (size_t)N * 128;         // x@W1 result; DEAD after spmm#1 -> reused for Shi/Slo
    float* h     = w; w += (size_t)N * 128;
    float* a     = w; w += (size_t)N * 128;
    float* aa    = w; w += (size_t)N * 128;
    float* t64   = w; w += (size_t)N * 64;
    float* az    = w; w += (size_t)N * 64;
    float* s     = w; w += (size_t)N * 64;
    float* dis   = w; w += N;
    float* valA  = w; w += (E + N);
    int* ip      = (int*)w;
    int* deg     = ip; ip += N;
    int* cursor  = ip; ip += N;
    int* rowptr  = ip; ip += N + 1;
    int* colA    = ip; ip += (E + N);

    // Shi/Slo alias t128a (N*128 floats = 5.1MB >= 2*Mpad*64*2B = 2.6MB)
    __hip_bfloat16* Shi = (__hip_bfloat16*)t128a;
    __hip_bfloat16* Slo = Shi + (size_t)Mpad * 64;

    dim3 b256(256);
    int mt = (N + 63) / 64;

    // CSR of A_norm (by recv), norm folded into vals
    k_init <<<dim3((N + 255) / 256), b256, 0, stream>>>(deg, cursor, N);
    k_count<<<dim3((E + 255) / 256), b256, 0, stream>>>(ei, deg, E);
    k_dis  <<<dim3((N + 255) / 256), b256, 0, stream>>>(deg, dis, N);
    k_scan <<<dim3(1), dim3(1024), 0, stream>>>(deg, rowptr, N);
    k_fill <<<dim3((E + N + 255) / 256), b256, 0, stream>>>(ei, rowptr, cursor, dis, colA, valA, N, E);

    // encoder: h = relu(A (x W1) + b1); z = relu(A (h W2) + b2)
    k_gemm<false, false><<<dim3(mt, HID / 64), b256, 0, stream>>>(x, W1, nullptr, t128a, N, IN_DIM, HID);
    k_spmm<128, true, true><<<dim3((N * 64 + 255) / 256), b256, 0, stream>>>(t128a, rowptr, colA, valA, b1, h, N);
    k_gemm<false, false><<<dim3(mt, LAT / 64), b256, 0, stream>>>(h, W2, nullptr, t64, N, HID, LAT);
    k_spmm<64, true, true><<<dim3((N * 64 + 255) / 256), b256, 0, stream>>>(t64, rowptr, colA, valA, b2, zout, N);

    // shared propagation: az = A z  (used by both decoders; exact reassociation of reference)
    k_spmm<64, false, false><<<dim3((N * 64 + 255) / 256), b256, 0, stream>>>(zout, rowptr, colA, valA, nullptr, az, N);

    // attribute decoder: a = relu(az Wa1 + ba1); attr = relu((A a) Wa2 + ba2)
    k_gemm<true, true><<<dim3(mt, HID / 64), b256, 0, stream>>>(az, Wa1, ba1, a, N, LAT, HID);
    k_spmm<128, false, false><<<dim3((N * 64 + 255) / 256), b256, 0, stream>>>(a, rowptr, colA, valA, nullptr, aa, N);
    k_gemm<true, true><<<dim3(mt, IN_DIM / 64), b256, 0, stream>>>(aa, Wa2, ba2, attr, N, HID, IN_DIM);

    // structure decoder: s = relu(az Ws + bs); struct = s s^T (split-bf16 MFMA)
    k_gemm<true, true><<<dim3(mt, LAT / 64), b256, 0, stream>>>(az, Ws, bs, s, N, LAT, LAT);
    k_split<<<dim3((Mpad * 64 + 255) / 256), b256, 0, stream>>>(s, Shi, Slo, N * 64, Mpad * 64);
    k_sst_mfma<<<dim3(Mpad / 128, Mpad / 128), b256, 0, stream>>>(Shi, Slo, st, N);
}

// Round 3
// 441.760 us; speedup vs baseline: 1.3637x; 1.0785x over previous
//
#include <hip/hip_runtime.h>
#include <hip/hip_bf16.h>

#define IN_DIM 1024
#define HID 128
#define LAT 64

typedef __attribute__((ext_vector_type(8))) short bf16x8;
typedef __attribute__((ext_vector_type(4))) float f32x4;

// ---------- CSR construction ----------

__global__ __launch_bounds__(256) void k_init(int* deg, int* cursor, int n) {
    int i = blockIdx.x * 256 + threadIdx.x;
    if (i < n) { deg[i] = 1; cursor[i] = 0; }   // deg starts at 1: self-loop
}

__global__ __launch_bounds__(256) void k_count(const int* __restrict__ ei, int* deg, int E) {
    int e = blockIdx.x * 256 + threadIdx.x;
    if (e < E) atomicAdd(&deg[ei[E + e]], 1);   // recv = ei[E + e]
}

__global__ __launch_bounds__(256) void k_dis(const int* __restrict__ deg, float* dis, int n) {
    int i = blockIdx.x * 256 + threadIdx.x;
    if (i < n) dis[i] = rsqrtf((float)deg[i]);
}

// 1024-thread single-block scan, shfl-based (few barriers)
__global__ __launch_bounds__(1024) void k_scan(const int* __restrict__ deg, int* __restrict__ rowptr, int n) {
    __shared__ int wsum[16];
    __shared__ int carry_sh;
    int t = threadIdx.x;
    int wave = t >> 6, lane = t & 63;
    if (t == 0) { carry_sh = 0; rowptr[0] = 0; }
    __syncthreads();
    int nch = (n + 1023) >> 10;
    for (int ch = 0; ch < nch; ++ch) {
        int i = (ch << 10) + t;
        int v = (i < n) ? deg[i] : 0;
        // wave inclusive scan
#pragma unroll
        for (int off = 1; off < 64; off <<= 1) {
            int u = __shfl_up(v, off, 64);
            if (lane >= off) v += u;
        }
        if (lane == 63) wsum[wave] = v;
        __syncthreads();
        if (wave == 0 && lane < 16) {
            int wv = wsum[lane];
#pragma unroll
            for (int off = 1; off < 16; off <<= 1) {
                int u = __shfl_up(wv, off, 64);
                if (lane >= off) wv += u;
            }
            wsum[lane] = wv;   // inclusive over waves
        }
        __syncthreads();
        int base = carry_sh + ((wave == 0) ? 0 : wsum[wave - 1]);
        if (i < n) rowptr[i + 1] = base + v;
        int total = wsum[15];
        __syncthreads();
        if (t == 0) carry_sh += total;
        __syncthreads();
    }
}

__global__ __launch_bounds__(256) void k_fill(const int* __restrict__ ei, const int* __restrict__ rowptr,
                                              int* cursor, const float* __restrict__ dis,
                                              int* __restrict__ colA, float* __restrict__ valA,
                                              int n, int E) {
    int e = blockIdx.x * 256 + threadIdx.x;
    if (e >= E + n) return;
    int s, r;
    if (e < E) { s = ei[e]; r = ei[E + e]; }
    else       { s = r = e - E; }            // self-loop
    int p = atomicAdd(&cursor[r], 1);
    int idx = rowptr[r] + p;
    colA[idx] = s;
    valA[idx] = dis[s] * dis[r];
}

// ---------- SpMM: out[i,:] = (bias) + sum_{p in row i} val[p] * H[col[p],:], optional relu ----------

template<int F, bool BIAS, bool RELU>
__global__ __launch_bounds__(256) void k_spmm(const float* __restrict__ H,
                                              const int* __restrict__ rowptr,
                                              const int* __restrict__ colA,
                                              const float* __restrict__ valA,
                                              const float* __restrict__ bias,
                                              float* __restrict__ out, int n) {
    int wave = (blockIdx.x * 256 + threadIdx.x) >> 6;
    int lane = threadIdx.x & 63;
    if (wave >= n) return;
    int p0 = rowptr[wave], p1 = rowptr[wave + 1];
    float acc[F / 64];
#pragma unroll
    for (int j = 0; j < F / 64; ++j) acc[j] = 0.f;
    for (int p = p0; p < p1; ++p) {
        int c = colA[p];
        float v = valA[p];
        const float* row = H + (size_t)c * F;
#pragma unroll
        for (int j = 0; j < F / 64; ++j) acc[j] = fmaf(v, row[lane + 64 * j], acc[j]);
    }
#pragma unroll
    for (int j = 0; j < F / 64; ++j) {
        float r = acc[j] + (BIAS ? bias[lane + 64 * j] : 0.f);
        if (RELU) r = fmaxf(r, 0.f);
        out[(size_t)wave * F + lane + 64 * j] = r;
    }
}

// ---------- Dense GEMM: C[M,Nc] = A[M,K] @ B[K,Nc] (+bias, relu). Nc % 64 == 0, K % 16 == 0 ----------

template<bool BIAS, bool RELU>
__global__ __launch_bounds__(256) void k_gemm(const float* __restrict__ A, const float* __restrict__ B,
                                              const float* __restrict__ bias, float* __restrict__ C,
                                              int M, int K, int Nc) {
    __shared__ float As[16][64];   // As[k][m] (transposed)
    __shared__ float Bs[16][64];   // Bs[k][n]
    int tid = threadIdx.x;
    int tx = tid & 15, ty = tid >> 4;
    int m0 = blockIdx.x * 64, n0 = blockIdx.y * 64;
    float acc[4][4] = {};

    for (int k0 = 0; k0 < K; k0 += 16) {
        {
            int idx = tid * 4;
            int r = idx >> 4;          // 0..63 (m within tile)
            int c = idx & 15;          // 0,4,8,12 (k within tile)
            int gr = m0 + r;
            float4 av = (gr < M) ? *(const float4*)&A[(size_t)gr * K + k0 + c]
                                 : make_float4(0.f, 0.f, 0.f, 0.f);
            As[c + 0][r] = av.x; As[c + 1][r] = av.y; As[c + 2][r] = av.z; As[c + 3][r] = av.w;
            int kk = idx >> 6;         // 0..15
            int cc = idx & 63;         // 0,4,..,60
            float4 bv = *(const float4*)&B[(size_t)(k0 + kk) * Nc + n0 + cc];
            *(float4*)&Bs[kk][cc] = bv;
        }
        __syncthreads();
#pragma unroll
        for (int kk = 0; kk < 16; ++kk) {
            float4 av = *(const float4*)&As[kk][ty * 4];
            float4 bv = *(const float4*)&Bs[kk][tx * 4];
            float aa[4] = {av.x, av.y, av.z, av.w};
            float bb[4] = {bv.x, bv.y, bv.z, bv.w};
#pragma unroll
            for (int i = 0; i < 4; ++i)
#pragma unroll
                for (int j = 0; j < 4; ++j)
                    acc[i][j] = fmaf(aa[i], bb[j], acc[i][j]);
        }
        __syncthreads();
    }

    int nbase = n0 + tx * 4;
    float bvals[4] = {0.f, 0.f, 0.f, 0.f};
    if (BIAS) {
#pragma unroll
        for (int j = 0; j < 4; ++j) bvals[j] = bias[nbase + j];
    }
#pragma unroll
    for (int i = 0; i < 4; ++i) {
        int gr = m0 + ty * 4 + i;
        if (gr < M) {
            float v0 = acc[i][0] + bvals[0];
            float v1 = acc[i][1] + bvals[1];
            float v2 = acc[i][2] + bvals[2];
            float v3 = acc[i][3] + bvals[3];
            if (RELU) {
                v0 = fmaxf(v0, 0.f); v1 = fmaxf(v1, 0.f);
                v2 = fmaxf(v2, 0.f); v3 = fmaxf(v3, 0.f);
            }
            *(float4*)&C[(size_t)gr * Nc + nbase] = make_float4(v0, v1, v2, v3);
        }
    }
}

// ---------- split fp32 -> (hi, lo) bf16 pair; zero-pads rows [M, Mpad) ----------

__global__ __launch_bounds__(256) void k_split(const float* __restrict__ s,
                                               __hip_bfloat16* __restrict__ hi,
                                               __hip_bfloat16* __restrict__ lo,
                                               int nvalid, int ntotal) {
    int i = blockIdx.x * 256 + threadIdx.x;
    if (i >= ntotal) return;
    float v = (i < nvalid) ? s[i] : 0.f;
    __hip_bfloat16 h = __float2bfloat16(v);
    hi[i] = h;
    lo[i] = __float2bfloat16(v - __bfloat162float(h));
}

// ---------- struct_recon = S @ S^T via split-bf16 MFMA ----------
// Upper-triangle blocks only (C symmetric); 128x128 block tile staged in 64KB LDS
// (XOR-swizzled at float4 granularity), streamed out as float4 rows for (bx,by)
// and as the transposed tile for (by,bx).

__device__ __forceinline__ int swz(int rl, int c4) { return (c4 ^ (rl & 31)); }

__global__ __launch_bounds__(256) void k_sst_mfma(const __hip_bfloat16* __restrict__ Shi,
                                                  const __hip_bfloat16* __restrict__ Slo,
                                                  float* __restrict__ C, int M) {
    int bx = blockIdx.x, by = blockIdx.y;
    if (by < bx) return;                       // upper triangle only
    __shared__ float tile[128 * 128];          // 64 KB

    int w = threadIdx.x >> 6, lane = threadIdx.x & 63;
    int wr = w >> 1, wc = w & 1;
    int i0 = bx * 128 + wr * 64;
    int j0 = by * 128 + wc * 64;
    int lrow = lane & 15;
    int lk = (lane >> 4) * 8;

    f32x4 acc[4][4] = {};   // [mi][nj]

#pragma unroll
    for (int ks = 0; ks < 2; ++ks) {
        bf16x8 ah[4], al[4], bh[4], bl[4];
#pragma unroll
        for (int mi = 0; mi < 4; ++mi) {
            size_t off = (size_t)(i0 + mi * 16 + lrow) * 64 + ks * 32 + lk;
            ah[mi] = *(const bf16x8*)(Shi + off);
            al[mi] = *(const bf16x8*)(Slo + off);
        }
#pragma unroll
        for (int nj = 0; nj < 4; ++nj) {
            size_t off = (size_t)(j0 + nj * 16 + lrow) * 64 + ks * 32 + lk;
            bh[nj] = *(const bf16x8*)(Shi + off);
            bl[nj] = *(const bf16x8*)(Slo + off);
        }
#pragma unroll
        for (int mi = 0; mi < 4; ++mi)
#pragma unroll
            for (int nj = 0; nj < 4; ++nj) {
                acc[mi][nj] = __builtin_amdgcn_mfma_f32_16x16x32_bf16(ah[mi], bh[nj], acc[mi][nj], 0, 0, 0);
                acc[mi][nj] = __builtin_amdgcn_mfma_f32_16x16x32_bf16(ah[mi], bl[nj], acc[mi][nj], 0, 0, 0);
                acc[mi][nj] = __builtin_amdgcn_mfma_f32_16x16x32_bf16(al[mi], bh[nj], acc[mi][nj], 0, 0, 0);
            }
    }

    // stage into LDS: C/D frag layout col=lane&15, row=(lane>>4)*4+r  [m89]
    int r0 = (lane >> 4) * 4;
#pragma unroll
    for (int mi = 0; mi < 4; ++mi)
#pragma unroll
        for (int nj = 0; nj < 4; ++nj) {
#pragma unroll
            for (int r = 0; r < 4; ++r) {
                int rl = wr * 64 + mi * 16 + r0 + r;
                int cl = wc * 64 + nj * 16 + lrow;
                tile[rl * 128 + (swz(rl, cl >> 2) << 2) + (cl & 3)] = acc[mi][nj][r];
            }
        }
    __syncthreads();

    int i0b = bx * 128, j0b = by * 128;
    int tt = threadIdx.x;

    // normal write: rows of (bx,by)
#pragma unroll
    for (int it = 0; it < 16; ++it) {
        int rl = it * 8 + (tt >> 5);
        int c4 = tt & 31;
        int row = i0b + rl;
        if (row >= M) continue;
        int col = j0b + c4 * 4;
        if (col >= M) continue;
        float4 v = *(const float4*)&tile[rl * 128 + (swz(rl, c4) << 2)];
        if (col + 3 < M) {
            *(float4*)&C[(size_t)row * M + col] = v;
        } else {
            float vv[4] = {v.x, v.y, v.z, v.w};
            for (int k = 0; k < 4 && col + k < M; ++k) C[(size_t)row * M + col + k] = vv[k];
        }
    }

    // transposed write: rows of (by,bx)
    if (bx != by) {
#pragma unroll
        for (int it = 0; it < 16; ++it) {
            int cl = it * 8 + (tt >> 5);       // tile column -> out row
            int row = j0b + cl;
            if (row >= M) continue;
            int rbase = (tt & 31) * 4;         // tile rows -> out cols
            int col = i0b + rbase;
            if (col >= M) continue;
            float vv[4];
#pragma unroll
            for (int k = 0; k < 4; ++k) {
                int rr = rbase + k;
                vv[k] = tile[rr * 128 + (swz(rr, cl >> 2) << 2) + (cl & 3)];
            }
            if (col + 3 < M) {
                *(float4*)&C[(size_t)row * M + col] = make_float4(vv[0], vv[1], vv[2], vv[3]);
            } else {
                for (int k = 0; k < 4 && col + k < M; ++k) C[(size_t)row * M + col + k] = vv[k];
            }
        }
    }
}

// ---------- launch ----------

extern "C" void kernel_launch(void* const* d_in, const int* in_sizes, int n_in,
                              void* d_out, int out_size, void* d_ws, size_t ws_size,
                              hipStream_t stream) {
    const float* x   = (const float*)d_in[0];
    const int*   ei  = (const int*)d_in[1];
    const float* W1  = (const float*)d_in[2];
    const float* b1  = (const float*)d_in[3];
    const float* W2  = (const float*)d_in[4];
    const float* b2  = (const float*)d_in[5];
    const float* Wa1 = (const float*)d_in[6];
    const float* ba1 = (const float*)d_in[7];
    const float* Wa2 = (const float*)d_in[8];
    const float* ba2 = (const float*)d_in[9];
    const float* Ws  = (const float*)d_in[10];
    const float* bs  = (const float*)d_in[11];

    int N = in_sizes[0] / IN_DIM;
    int E = in_sizes[1] / 2;
    int Mpad = ((N + 127) / 128) * 128;

    float* out  = (float*)d_out;
    float* attr = out;                              // [N, IN_DIM]
    float* st   = out + (size_t)N * IN_DIM;         // [N, N]
    float* zout = st + (size_t)N * N;               // [N, LAT]

    float* w = (float*)d_ws;
    float* t128a = w; w += (size_t)N * 128;         // x@W1 result; DEAD after spmm#1 -> reused for Shi/Slo
    float* h     = w; w += (size_t)N * 128;
    float* a     = w; w += (size_t)N * 128;
    float* aa    = w; w += (size_t)N * 128;
    float* t64   = w; w += (size_t)N * 64;
    float* az    = w; w += (size_t)N * 64;
    float* s     = w; w += (size_t)N * 64;
    float* dis   = w; w += N;
    float* valA  = w; w += (E + N);
    int* ip      = (int*)w;
    int* deg     = ip; ip += N;
    int* cursor  = ip; ip += N;
    int* rowptr  = ip; ip += N + 1;
    int* colA    = ip; ip += (E + N);

    // Shi/Slo alias t128a (N*128 floats = 5.1MB >= 2*Mpad*64*2B = 2.6MB)
    __hip_bfloat16* Shi = (__hip_bfloat16*)t128a;
    __hip_bfloat16* Slo = Shi + (size_t)Mpad * 64;

    dim3 b256(256);
    int mt = (N + 63) / 64;

    // CSR of A_norm (by recv), norm folded into vals
    k_init <<<dim3((N + 255) / 256), b256, 0, stream>>>(deg, cursor, N);
    k_count<<<dim3((E + 255) / 256), b256, 0, stream>>>(ei, deg, E);
    k_dis  <<<dim3((N + 255) / 256), b256, 0, stream>>>(deg, dis, N);
    k_scan <<<dim3(1), dim3(1024), 0, stream>>>(deg, rowptr, N);
    k_fill <<<dim3((E + N + 255) / 256), b256, 0, stream>>>(ei, rowptr, cursor, dis, colA, valA, N, E);

    // encoder: h = relu(A (x W1) + b1); z = relu(A (h W2) + b2)
    k_gemm<false, false><<<dim3(mt, HID / 64), b256, 0, stream>>>(x, W1, nullptr, t128a, N, IN_DIM, HID);
    k_spmm<128, true, true><<<dim3((N * 64 + 255) / 256), b256, 0, stream>>>(t128a, rowptr, colA, valA, b1, h, N);
    k_gemm<false, false><<<dim3(mt, LAT / 64), b256, 0, stream>>>(h, W2, nullptr, t64, N, HID, LAT);
    k_spmm<64, true, true><<<dim3((N * 64 + 255) / 256), b256, 0, stream>>>(t64, rowptr, colA, valA, b2, zout, N);

    // shared propagation: az = A z  (used by both decoders; exact reassociation of reference)
    k_spmm<64, false, false><<<dim3((N * 64 + 255) / 256), b256, 0, stream>>>(zout, rowptr, colA, valA, nullptr, az, N);

    // attribute decoder: a = relu(az Wa1 + ba1); attr = relu((A a) Wa2 + ba2)
    k_gemm<true, true><<<dim3(mt, HID / 64), b256, 0, stream>>>(az, Wa1, ba1, a, N, LAT, HID);
    k_spmm<128, false, false><<<dim3((N * 64 + 255) / 256), b256, 0, stream>>>(a, rowptr, colA, valA, nullptr, aa, N);
    k_gemm<true, true><<<dim3(mt, IN_DIM / 64), b256, 0, stream>>>(aa, Wa2, ba2, attr, N, HID, IN_DIM);

    // structure decoder: s = relu(az Ws + bs); struct = s s^T (split-bf16 MFMA, symmetric)
    k_gemm<true, true><<<dim3(mt, LAT / 64), b256, 0, stream>>>(az, Ws, bs, s, N, LAT, LAT);
    k_split<<<dim3((Mpad * 64 + 255) / 256), b256, 0, stream>>>(s, Shi, Slo, N * 64, Mpad * 64);
    k_sst_mfma<<<dim3(Mpad / 128, Mpad / 128), b256, 0, stream>>>(Shi, Slo, st, N);
}